// Round 3
// baseline (260.180 us; speedup 1.0000x reference)
//
#include <hip/hip_runtime.h>
#include <math.h>

#define DD 5          // embedding dim
#define EST 8         // emb row stride (padded 5 -> 8 floats, 32B rows)
#define NFREQ 50      // frequencies per coordinate
#define NB 128        // sort blocks
// ENC_DIM = 4*NFREQ = 200; W row per gene = 200*5 = 1000 floats

// ---------------------------------------------------------------- K1: hist + out-init
// Blocks < NB histogram their contiguous chunk into LDS and write per-block
// counts bc[b][g] (coalesced). ALL blocks grid-stride the 20MB out <- bias
// broadcast. No tickets, no global atomics: the per-block counts are combined
// redundantly by each scatter block in K2.
__global__ __launch_bounds__(256) void hist_init_kernel(
    const int* __restrict__ gm, int F, int chunk,
    int* __restrict__ bc, int n_genes,
    float* __restrict__ out, const float* __restrict__ bias,
    const int* __restrict__ genes_oi, int total4) {
  __shared__ int cnt[1000];
  const int gtid = blockIdx.x * blockDim.x + threadIdx.x;
  const int gs = gridDim.x * blockDim.x;
  // block-local histogram (first NB blocks)
  if (blockIdx.x < NB) {
    for (int j = threadIdx.x; j < n_genes; j += blockDim.x) cnt[j] = 0;
    __syncthreads();
    int lo = blockIdx.x * chunk;
    int hi = min(F, lo + chunk);
    for (int i = lo + threadIdx.x; i < hi; i += blockDim.x)
      atomicAdd(&cnt[gm[i]], 1);
    __syncthreads();
    int* dst = bc + (size_t)blockIdx.x * n_genes;
    for (int j = threadIdx.x; j < n_genes; j += blockDim.x)
      dst[j] = cnt[j];
  }
  // out <- bias broadcast (row-repeating; n_genes % 4 == 0 -> same row per float4)
  for (int v4 = gtid; v4 < total4; v4 += gs) {
    int idx = v4 * 4;
    int j = idx % n_genes;
    float4 vv;
    vv.x = bias[genes_oi[j + 0]];
    vv.y = bias[genes_oi[j + 1]];
    vv.z = bias[genes_oi[j + 2]];
    vv.w = bias[genes_oi[j + 3]];
    reinterpret_cast<float4*>(out)[v4] = vv;
  }
}

// ---------------------------------------------------------------- K2: offsets + scatter
// Each block b independently: sums bc over all blocks (totals) and over blocks
// b' < b (its prefix), shfl-scans totals -> starts, seeds LDS cursors
// cur[g] = starts[g] + prefix_b[g], then scatters its chunk with LDS atomics.
// Block 0 also publishes starts[] for the embed kernel. 512KB of redundant
// bc reads are L2-resident broadcast — cheaper than a ticket/extra kernel.
__global__ __launch_bounds__(256) void scatter_kernel(
    const int* __restrict__ gm, int F, int chunk,
    const int* __restrict__ bc, int n_genes,
    int* __restrict__ order, int* __restrict__ starts) {
  __shared__ int s_tot[1024];   // padded to 1024, int4-scannable
  __shared__ int s_pref[1000];
  __shared__ int s_cur[1000];
  __shared__ int s_ws[4];
  const int tid = threadIdx.x;
  const int b = blockIdx.x;
  // zero pad region
  if (tid < 24) s_tot[1000 + tid] = 0;
  // accumulate totals + own prefix (4 genes per thread, coalesced over bc rows)
  int tot[4] = {0, 0, 0, 0}, pre[4] = {0, 0, 0, 0};
  for (int bp = 0; bp < NB; ++bp) {
    const int* __restrict__ row = bc + (size_t)bp * n_genes;
#pragma unroll
    for (int j = 0; j < 4; ++j) {
      int g = tid + 256 * j;
      if (g < n_genes) {
        int v = row[g];
        tot[j] += v;
        if (bp < b) pre[j] += v;
      }
    }
  }
#pragma unroll
  for (int j = 0; j < 4; ++j) {
    int g = tid + 256 * j;
    if (g < n_genes) {
      s_tot[g] = tot[j];
      s_pref[g] = pre[j];
    }
  }
  __syncthreads();
  // exclusive scan of totals (thread t holds genes 4t..4t+3)
  int lane = tid & 63, wv = tid >> 6;
  int4 v = ((const int4*)s_tot)[tid];
  int p = v.x + v.y + v.z + v.w;
  int ip = p;
#pragma unroll
  for (int off = 1; off < 64; off <<= 1) {
    int q = __shfl_up(ip, off);
    if (lane >= off) ip += q;
  }
  if (lane == 63) s_ws[wv] = ip;
  __syncthreads();
  int add = 0;
#pragma unroll
  for (int i = 0; i < 4; ++i)
    if (i < wv) add += s_ws[i];
  int excl = add + ip - p;
  int4 e;
  e.x = excl;
  e.y = excl + v.x;
  e.z = e.y + v.y;
  e.w = e.z + v.z;
  if (4 * tid < n_genes) {
    s_cur[4 * tid + 0] = e.x + s_pref[4 * tid + 0];
    s_cur[4 * tid + 1] = e.y + s_pref[4 * tid + 1];
    s_cur[4 * tid + 2] = e.z + s_pref[4 * tid + 2];
    s_cur[4 * tid + 3] = e.w + s_pref[4 * tid + 3];
    if (b == 0) {
      ((int4*)starts)[tid] = e;
      if (4 * tid + 4 == n_genes) starts[n_genes] = e.w + v.w;   // == F
    }
  }
  __syncthreads();
  // scatter this block's chunk via LDS cursors
  int lo = b * chunk;
  int hi = min(F, lo + chunk);
  for (int i = lo + tid; i < hi; i += blockDim.x) {
    int g = gm[i];
    int pos = atomicAdd(&s_cur[g], 1);
    order[pos] = i;
  }
}

// ---------------------------------------------------------------- K3: fragment embedding
// One block per gene: W addresses are wave-uniform -> scalar (SMEM) loads.
// Frequency table hoisted to LDS. emb rows padded to 8 floats -> float4 stores.
__global__ __launch_bounds__(256) void embed_kernel(
    const float2* __restrict__ coords, const int* __restrict__ order,
    const int* __restrict__ starts, const float* __restrict__ W,
    float* __restrict__ emb) {
  __shared__ float s_freq[NFREQ];
  if (threadIdx.x < NFREQ)
    s_freq[threadIdx.x] = exp2f(-0.39863137f * (float)(threadIdx.x + 1));
  __syncthreads();
  int g = blockIdx.x;
  int s0 = starts[g];
  int s1 = starts[g + 1];
  const float* __restrict__ Wg = W + (size_t)g * (4 * NFREQ * DD);

  for (int i = s0 + threadIdx.x; i < s1; i += blockDim.x) {
    int f = order[i];
    float2 xy = coords[f];
    float a0 = 0.f, a1 = 0.f, a2 = 0.f, a3 = 0.f, a4 = 0.f;
    for (int k = 0; k < NFREQ; ++k) {
      float fr = s_freq[k];
      float ax = xy.x * fr;
      float ay = xy.y * fr;
      float sx = __sinf(ax), cx = __cosf(ax);
      float sy = __sinf(ay), cy = __cosf(ay);
      const float* w0s = Wg + (2 * k) * DD;               // coord0 sin row
      const float* w0c = w0s + DD;                        // coord0 cos row
      const float* w1s = Wg + (2 * NFREQ + 2 * k) * DD;   // coord1 sin row
      const float* w1c = w1s + DD;                        // coord1 cos row
      a0 += sx * w0s[0] + cx * w0c[0] + sy * w1s[0] + cy * w1c[0];
      a1 += sx * w0s[1] + cx * w0c[1] + sy * w1s[1] + cy * w1c[1];
      a2 += sx * w0s[2] + cx * w0c[2] + sy * w1s[2] + cy * w1c[2];
      a3 += sx * w0s[3] + cx * w0c[3] + sy * w1s[3] + cy * w1c[3];
      a4 += sx * w0s[4] + cx * w0c[4] + sy * w1s[4] + cy * w1c[4];
    }
    float* e = emb + (size_t)f * EST;
    float4 r;
    r.x = 1.f / (1.f + __expf(-a0));
    r.y = 1.f / (1.f + __expf(-a1));
    r.z = 1.f / (1.f + __expf(-a2));
    r.w = 1.f / (1.f + __expf(-a3));
    *reinterpret_cast<float4*>(e) = r;
    e[4] = 1.f / (1.f + __expf(-a4));
  }
}

// ---------------------------------------------------------------- attention group, DELTA pool
// The raw-pool pass (below) adds x.w for EVERY fragment; group threads add
// only the correction (o - x).w — no membership mask needed anywhere.
template <int SZ>
__device__ __forceinline__ void attn_group_delta(const int* __restrict__ idx,
                                                 const float* __restrict__ emb,
                                                 const int* __restrict__ lci,
                                                 const int* __restrict__ genes_oi,
                                                 const float* __restrict__ wexpr,
                                                 int n_genes, float* __restrict__ out) {
  int fid[SZ];
  float x[SZ][DD];
#pragma unroll
  for (int a = 0; a < SZ; ++a) {
    fid[a] = idx[a];
    const float* p = emb + (size_t)fid[a] * EST;
    float4 v = *reinterpret_cast<const float4*>(p);
    x[a][0] = v.x; x[a][1] = v.y; x[a][2] = v.z; x[a][3] = v.w;
    x[a][4] = p[4];
  }
  const float scale = rsqrtf((float)SZ);   // reference scales by sqrt(seq_len)
#pragma unroll
  for (int a = 0; a < SZ; ++a) {
    float sc[SZ];
    float m = -1e30f;
#pragma unroll
    for (int b = 0; b < SZ; ++b) {
      float dt = 0.f;
#pragma unroll
      for (int d = 0; d < DD; ++d) dt += x[a][d] * x[b][d];
      sc[b] = dt * scale;
      m = fmaxf(m, sc[b]);
    }
    float sum = 0.f;
#pragma unroll
    for (int b = 0; b < SZ; ++b) {
      sc[b] = __expf(sc[b] - m);
      sum += sc[b];
    }
    float inv = 1.f / sum;
    int ix = lci[fid[a]];
    int g = genes_oi[ix % n_genes];
    const float* w = wexpr + (size_t)g * DD;
    float s = 0.f;
#pragma unroll
    for (int d = 0; d < DD; ++d) {
      float acc = 0.f;
#pragma unroll
      for (int b = 0; b < SZ; ++b) acc += sc[b] * x[b][d];
      s += (acc * inv - x[a][d]) * w[d];
    }
    atomicAdd(out + ix, s);
  }
}

// ---------------------------------------------------------------- K4: attention + pool-all
// Raw pooling of every fragment's emb (branchless, coalesced), plus delta
// corrections from the attention groups. out already holds bias (K1).
__global__ __launch_bounds__(256) void attn_pool_kernel(
    const int* __restrict__ n2, int g2,
    const int* __restrict__ n3, int g3,
    const int* __restrict__ n4, int g4,
    const float* __restrict__ emb, const int* __restrict__ lci,
    const int* __restrict__ genes_oi, const float* __restrict__ wexpr,
    int F, int n_genes, float* __restrict__ out) {
  int gtid = blockIdx.x * blockDim.x + threadIdx.x;
  int gs = gridDim.x * blockDim.x;
  int gtot = g2 + g3 + g4;
  for (int w = gtid; w < gtot; w += gs) {
    if (w < g2)
      attn_group_delta<2>(n2 + (size_t)w * 2, emb, lci, genes_oi, wexpr, n_genes, out);
    else if (w < g2 + g3)
      attn_group_delta<3>(n3 + (size_t)(w - g2) * 3, emb, lci, genes_oi, wexpr, n_genes, out);
    else
      attn_group_delta<4>(n4 + (size_t)(w - g2 - g3) * 4, emb, lci, genes_oi, wexpr, n_genes, out);
  }
  for (int f = gtid; f < F; f += gs) {
    int ix = lci[f];
    int g = genes_oi[ix % n_genes];
    const float* e = emb + (size_t)f * EST;
    float4 v = *reinterpret_cast<const float4*>(e);
    const float* w = wexpr + (size_t)g * DD;
    float s = v.x * w[0] + v.y * w[1] + v.z * w[2] + v.w * w[3] + e[4] * w[4];
    atomicAdd(out + ix, s);
  }
}

// ---------------------------------------------------------------- launch
extern "C" void kernel_launch(void* const* d_in, const int* in_sizes, int n_in,
                              void* d_out, int out_size, void* d_ws, size_t ws_size,
                              hipStream_t stream) {
  const float2* coords  = (const float2*)d_in[0];
  const int* gm         = (const int*)d_in[1];
  const int* n2         = (const int*)d_in[2];
  const int* n3         = (const int*)d_in[3];
  const int* n4         = (const int*)d_in[4];
  const int* lci        = (const int*)d_in[5];
  const int* genes_oi   = (const int*)d_in[6];
  const float* W        = (const float*)d_in[7];
  const float* wexpr    = (const float*)d_in[8];
  const float* bias     = (const float*)d_in[9];
  float* out            = (float*)d_out;

  const int F       = in_sizes[1];
  const int n_genes = in_sizes[6];
  const int g2 = in_sizes[2] / 2;
  const int g3 = in_sizes[3] / 3;
  const int g4 = in_sizes[4] / 4;

  char* ws = (char*)d_ws;
  size_t off = 0;
  float* emb   = (float*)(ws + off); off += (size_t)F * EST * sizeof(float);
  int* order   = (int*)(ws + off);   off += (size_t)F * sizeof(int);
  int* bc      = (int*)(ws + off);   off += (size_t)NB * n_genes * sizeof(int);
  off = (off + 15) & ~(size_t)15;
  int* starts  = (int*)(ws + off);   off += (size_t)(n_genes + 4) * sizeof(int);

  const int tb = 256;
  const int chunk = (F + NB - 1) / NB;
  const int total4 = out_size / 4;

  hist_init_kernel<<<1024, tb, 0, stream>>>(gm, F, chunk, bc, n_genes,
                                            out, bias, genes_oi, total4);
  scatter_kernel<<<NB, tb, 0, stream>>>(gm, F, chunk, bc, n_genes, order, starts);
  embed_kernel<<<n_genes, tb, 0, stream>>>(coords, order, starts, W, emb);
  attn_pool_kernel<<<1024, tb, 0, stream>>>(n2, g2, n3, g3, n4, g4,
                                            emb, lci, genes_oi, wexpr,
                                            F, n_genes, out);
}

// Round 4
// 146.568 us; speedup vs baseline: 1.7752x; 1.7752x over previous
//
#include <hip/hip_runtime.h>
#include <math.h>

#define DD 5          // embedding dim
#define EST 8         // emb row stride (padded 5 -> 8 floats, 32B rows)
#define NFREQ 50      // frequencies per coordinate
#define NB 128        // sort blocks
// ENC_DIM = 4*NFREQ = 200; W row per gene = 200*5 = 1000 floats

// ---------------------------------------------------------------- K1: hist + out-init
// Blocks < NB histogram their contiguous chunk into LDS, write per-block counts
// transposed bc[g*NB+b] (proven binscan layout). ALL blocks: build the 1000-float
// bias row ONCE in LDS, then stream pure float4 row-stores for out <- bias
// (kills the 8-loads-per-float4 gather of the old init). Also zeroes the ticket.
__global__ __launch_bounds__(256) void hist_init_kernel(
    const int* __restrict__ gm, int F, int chunk,
    int* __restrict__ bc, int n_genes, int* __restrict__ done,
    float* __restrict__ out, const float* __restrict__ bias,
    const int* __restrict__ genes_oi, int n_cells) {
  __shared__ int cnt[1000];
  __shared__ float s_brow[1000];
  const int tid = threadIdx.x;
  if (blockIdx.x == 0 && tid == 0) *done = 0;
  for (int j = tid; j < n_genes; j += blockDim.x) {
    s_brow[j] = bias[genes_oi[j]];
    cnt[j] = 0;
  }
  __syncthreads();
  // block-local histogram (first NB blocks)
  if (blockIdx.x < NB) {
    int lo = blockIdx.x * chunk;
    int hi = min(F, lo + chunk);
    for (int i = lo + tid; i < hi; i += blockDim.x)
      atomicAdd(&cnt[gm[i]], 1);
  }
  // out <- bias row broadcast: pure float4 stores from LDS (n_genes % 4 == 0)
  const float4* b4 = (const float4*)s_brow;
  const int q = n_genes >> 2;          // 250 float4 per row
  for (int c = blockIdx.x; c < n_cells; c += gridDim.x) {
    float4* dst = (float4*)out + (size_t)c * q;
    for (int t = tid; t < q; t += blockDim.x) dst[t] = b4[t];
  }
  __syncthreads();
  if (blockIdx.x < NB)
    for (int j = tid; j < n_genes; j += blockDim.x)
      bc[j * NB + blockIdx.x] = cnt[j];
}

// ---------------------------------------------------------------- K2: per-bin scan + starts
// One wave per bin (4 bins/block): exclusive-scan the bin's NB=128 block counts
// in-register (int2 + shfl), emit bin total. LAST block (device ticket) scans
// the 1000 bin totals -> starts[]. (Proven 142.9us config, mask work removed.)
__global__ __launch_bounds__(256) void binscan_starts_kernel(
    int* __restrict__ bc, int n_genes, int* __restrict__ totals,
    int* __restrict__ starts, int* __restrict__ done, int nblocks) {
  __shared__ int s_amlast;
  __shared__ int s_ws[4];
  int lane = threadIdx.x & 63;
  int wv = threadIdx.x >> 6;               // 0..3
  int bin = blockIdx.x * 4 + wv;
  if (bin < n_genes) {
    int2* row = (int2*)(bc + (size_t)bin * NB);   // 64 int2 per row
    int2 v = row[lane];
    int p = v.x + v.y;
    int ip = p;
#pragma unroll
    for (int off = 1; off < 64; off <<= 1) {
      int q = __shfl_up(ip, off);
      if (lane >= off) ip += q;
    }
    int base = ip - p;                      // exclusive prefix of this lane's pair
    int2 e;
    e.x = base;
    e.y = base + v.x;
    row[lane] = e;
    if (lane == 63) totals[bin] = ip;
  }
  __syncthreads();
  if (threadIdx.x == 0) {
    __threadfence();                        // publish totals
    int tk = atomicAdd(done, 1);
    s_amlast = (tk == nblocks - 1);
  }
  __syncthreads();
  if (!s_amlast) return;
  __threadfence();                          // acquire all totals
  // ---- scan 1000 totals with this block (n_genes % 4 == 0)
  int t = threadIdx.x;
  int4 v = make_int4(0, 0, 0, 0);
  if (4 * t < n_genes) v = ((const int4*)totals)[t];
  int p = v.x + v.y + v.z + v.w;
  int ip = p;
#pragma unroll
  for (int off = 1; off < 64; off <<= 1) {
    int q = __shfl_up(ip, off);
    if (lane >= off) ip += q;
  }
  if (lane == 63) s_ws[wv] = ip;
  __syncthreads();
  int add = 0;
#pragma unroll
  for (int i = 0; i < 4; ++i)
    if (i < wv) add += s_ws[i];
  int excl = add + ip - p;
  int4 e;
  e.x = excl;
  e.y = excl + v.x;
  e.z = e.y + v.y;
  e.w = e.z + v.z;
  if (4 * t < n_genes) ((int4*)starts)[t] = e;
  if (4 * t + 4 == n_genes) starts[n_genes] = e.w + v.w;   // grand total
}

// ---------------------------------------------------------------- K3: scatter by gene
// LDS cursors seeded with this block's global offset per bin; LDS atomics only.
__global__ __launch_bounds__(256) void blockscatter_kernel(
    const int* __restrict__ gm, int F, int chunk,
    const int* __restrict__ bc, const int* __restrict__ starts,
    int* __restrict__ order, int n_genes) {
  __shared__ int cur[1000];
  int b = blockIdx.x;
  for (int j = threadIdx.x; j < n_genes; j += blockDim.x)
    cur[j] = starts[j] + bc[j * NB + b];
  __syncthreads();
  int lo = b * chunk;
  int hi = min(F, lo + chunk);
  for (int i = lo + threadIdx.x; i < hi; i += blockDim.x) {
    int g = gm[i];
    int p = atomicAdd(&cur[g], 1);
    order[p] = i;
  }
}

// ---------------------------------------------------------------- K4: fragment embedding
// One block per gene. The gene's 4KB W row is staged in LDS, REPACKED so each
// k-iteration's 20 weights are contiguous: per iter = 5 broadcast ds_read_b128
// + 20 FMA. This removes the 20-scalar-loads-per-iteration dependency chain
// that made the old version latency-bound.
// Packed element e (0..19) at k: e<10 -> W[10k+e] ; e>=10 -> W[500+10k+(e-10)].
__global__ __launch_bounds__(256) void embed_kernel(
    const float2* __restrict__ coords, const int* __restrict__ order,
    const int* __restrict__ starts, const float* __restrict__ W,
    float* __restrict__ emb, int n_genes) {
  __shared__ float s_w[1000];
  __shared__ float s_freq[NFREQ];
  const int tid = threadIdx.x;
  if (tid < NFREQ)
    s_freq[tid] = exp2f(-0.39863137f * (float)(tid + 1));
  int g = blockIdx.x;
  const float* __restrict__ Wg = W + (size_t)g * (4 * NFREQ * DD);
  for (int idx = tid; idx < 1000; idx += blockDim.x) {
    int k = idx / 20, r = idx % 20;
    s_w[idx] = (r < 10) ? Wg[10 * k + r] : Wg[500 + 10 * k + (r - 10)];
  }
  __syncthreads();
  int s0 = starts[g];
  int s1 = starts[g + 1];
  const float4* __restrict__ w4 = (const float4*)s_w;

  for (int i = s0 + tid; i < s1; i += blockDim.x) {
    int f = order[i];
    float2 xy = coords[f];
    float a0 = 0.f, a1 = 0.f, a2 = 0.f, a3 = 0.f, a4 = 0.f;
#pragma unroll 2
    for (int k = 0; k < NFREQ; ++k) {
      float fr = s_freq[k];
      float ax = xy.x * fr;
      float ay = xy.y * fr;
      float sx = __sinf(ax), cx = __cosf(ax);
      float sy = __sinf(ay), cy = __cosf(ay);
      float4 c0 = w4[5 * k + 0];   // e0..e3   = w0s[0..3]
      float4 c1 = w4[5 * k + 1];   // e4..e7   = w0s[4], w0c[0..2]
      float4 c2 = w4[5 * k + 2];   // e8..e11  = w0c[3..4], w1s[0..1]
      float4 c3 = w4[5 * k + 3];   // e12..e15 = w1s[2..4], w1c[0]
      float4 c4 = w4[5 * k + 4];   // e16..e19 = w1c[1..4]
      a0 += sx * c0.x + cx * c1.y + sy * c2.z + cy * c3.w;
      a1 += sx * c0.y + cx * c1.z + sy * c2.w + cy * c4.x;
      a2 += sx * c0.z + cx * c1.w + sy * c3.x + cy * c4.y;
      a3 += sx * c0.w + cx * c2.x + sy * c3.y + cy * c4.z;
      a4 += sx * c1.x + cx * c2.y + sy * c3.z + cy * c4.w;
    }
    float* e = emb + (size_t)f * EST;
    float4 r;
    r.x = 1.f / (1.f + __expf(-a0));
    r.y = 1.f / (1.f + __expf(-a1));
    r.z = 1.f / (1.f + __expf(-a2));
    r.w = 1.f / (1.f + __expf(-a3));
    *reinterpret_cast<float4*>(e) = r;
    e[4] = 1.f / (1.f + __expf(-a4));
  }
}

// ---------------------------------------------------------------- attention group, DELTA pool
// The raw-pool pass adds x.w for EVERY fragment; group threads add only the
// correction (o - x).w — no membership mask needed anywhere (validated r3).
template <int SZ>
__device__ __forceinline__ void attn_group_delta(const int* __restrict__ idx,
                                                 const float* __restrict__ emb,
                                                 const int* __restrict__ lci,
                                                 const int* __restrict__ genes_oi,
                                                 const float* __restrict__ wexpr,
                                                 int n_genes, float* __restrict__ out) {
  int fid[SZ];
  float x[SZ][DD];
#pragma unroll
  for (int a = 0; a < SZ; ++a) {
    fid[a] = idx[a];
    const float* p = emb + (size_t)fid[a] * EST;
    float4 v = *reinterpret_cast<const float4*>(p);
    x[a][0] = v.x; x[a][1] = v.y; x[a][2] = v.z; x[a][3] = v.w;
    x[a][4] = p[4];
  }
  const float scale = rsqrtf((float)SZ);   // reference scales by sqrt(seq_len)
#pragma unroll
  for (int a = 0; a < SZ; ++a) {
    float sc[SZ];
    float m = -1e30f;
#pragma unroll
    for (int b = 0; b < SZ; ++b) {
      float dt = 0.f;
#pragma unroll
      for (int d = 0; d < DD; ++d) dt += x[a][d] * x[b][d];
      sc[b] = dt * scale;
      m = fmaxf(m, sc[b]);
    }
    float sum = 0.f;
#pragma unroll
    for (int b = 0; b < SZ; ++b) {
      sc[b] = __expf(sc[b] - m);
      sum += sc[b];
    }
    float inv = 1.f / sum;
    int ix = lci[fid[a]];
    int g = genes_oi[ix % n_genes];
    const float* w = wexpr + (size_t)g * DD;
    float s = 0.f;
#pragma unroll
    for (int d = 0; d < DD; ++d) {
      float acc = 0.f;
#pragma unroll
      for (int b = 0; b < SZ; ++b) acc += sc[b] * x[b][d];
      s += (acc * inv - x[a][d]) * w[d];
    }
    atomicAdd(out + ix, s);
  }
}

// ---------------------------------------------------------------- K5: attention + pool-all
// Raw pooling of every fragment's emb (branchless, coalesced), plus delta
// corrections from the attention groups. out already holds bias (K1).
__global__ __launch_bounds__(256) void attn_pool_kernel(
    const int* __restrict__ n2, int g2,
    const int* __restrict__ n3, int g3,
    const int* __restrict__ n4, int g4,
    const float* __restrict__ emb, const int* __restrict__ lci,
    const int* __restrict__ genes_oi, const float* __restrict__ wexpr,
    int F, int n_genes, float* __restrict__ out) {
  int gtid = blockIdx.x * blockDim.x + threadIdx.x;
  int gs = gridDim.x * blockDim.x;
  int gtot = g2 + g3 + g4;
  for (int w = gtid; w < gtot; w += gs) {
    if (w < g2)
      attn_group_delta<2>(n2 + (size_t)w * 2, emb, lci, genes_oi, wexpr, n_genes, out);
    else if (w < g2 + g3)
      attn_group_delta<3>(n3 + (size_t)(w - g2) * 3, emb, lci, genes_oi, wexpr, n_genes, out);
    else
      attn_group_delta<4>(n4 + (size_t)(w - g2 - g3) * 4, emb, lci, genes_oi, wexpr, n_genes, out);
  }
  for (int f = gtid; f < F; f += gs) {
    int ix = lci[f];
    int g = genes_oi[ix % n_genes];
    const float* e = emb + (size_t)f * EST;
    float4 v = *reinterpret_cast<const float4*>(e);
    const float* w = wexpr + (size_t)g * DD;
    float s = v.x * w[0] + v.y * w[1] + v.z * w[2] + v.w * w[3] + e[4] * w[4];
    atomicAdd(out + ix, s);
  }
}

// ---------------------------------------------------------------- launch
extern "C" void kernel_launch(void* const* d_in, const int* in_sizes, int n_in,
                              void* d_out, int out_size, void* d_ws, size_t ws_size,
                              hipStream_t stream) {
  const float2* coords  = (const float2*)d_in[0];
  const int* gm         = (const int*)d_in[1];
  const int* n2         = (const int*)d_in[2];
  const int* n3         = (const int*)d_in[3];
  const int* n4         = (const int*)d_in[4];
  const int* lci        = (const int*)d_in[5];
  const int* genes_oi   = (const int*)d_in[6];
  const float* W        = (const float*)d_in[7];
  const float* wexpr    = (const float*)d_in[8];
  const float* bias     = (const float*)d_in[9];
  float* out            = (float*)d_out;

  const int F       = in_sizes[1];
  const int n_genes = in_sizes[6];
  const int g2 = in_sizes[2] / 2;
  const int g3 = in_sizes[3] / 3;
  const int g4 = in_sizes[4] / 4;

  char* ws = (char*)d_ws;
  size_t off = 0;
  float* emb   = (float*)(ws + off); off += (size_t)F * EST * sizeof(float);
  int* order   = (int*)(ws + off);   off += (size_t)F * sizeof(int);
  int* bc      = (int*)(ws + off);   off += (size_t)n_genes * NB * sizeof(int);
  off = (off + 15) & ~(size_t)15;
  int* starts  = (int*)(ws + off);   off += (size_t)(n_genes + 4) * sizeof(int);
  off = (off + 15) & ~(size_t)15;
  int* totals  = (int*)(ws + off);   off += (size_t)n_genes * sizeof(int);
  int* done    = (int*)(ws + off);   off += 4 * sizeof(int);

  const int tb = 256;
  const int chunk = (F + NB - 1) / NB;
  const int n_cells = out_size / n_genes;   // out_size in floats

  hist_init_kernel<<<1024, tb, 0, stream>>>(gm, F, chunk, bc, n_genes, done,
                                            out, bias, genes_oi, n_cells);
  int scan_blocks = (n_genes + 3) / 4;    // one wave per bin, 4 bins/block
  binscan_starts_kernel<<<scan_blocks, tb, 0, stream>>>(bc, n_genes, totals,
                                                        starts, done, scan_blocks);
  blockscatter_kernel<<<NB, tb, 0, stream>>>(gm, F, chunk, bc, starts, order, n_genes);
  embed_kernel<<<n_genes, tb, 0, stream>>>(coords, order, starts, W, emb, n_genes);
  attn_pool_kernel<<<1024, tb, 0, stream>>>(n2, g2, n3, g3, n4, g4,
                                            emb, lci, genes_oi, wexpr,
                                            F, n_genes, out);
}